// Round 18
// baseline (364.322 us; speedup 1.0000x reference)
//
#include <hip/hip_runtime.h>
#include <hip/hip_bf16.h>
#include <stdint.h>

#define BB 8
#define LL 4096
#define DD 64
#define KT 64
#define NT (LL / KT)         // 64 pass-1 tiles
#define NP2 (LL / 128)       // 32 pass-2 tiles (128 wide)

typedef short bf16x8 __attribute__((ext_vector_type(8)));
typedef float f32x4 __attribute__((ext_vector_type(4)));

#define QSCALE 0.1803368801111204f   // (1/8)*log2(e): folds scale + exp->exp2

__device__ inline short f2bfs(float x) {
    __hip_bfloat16 h = __float2bfloat16(x);
    return __builtin_bit_cast(short, h);
}

__device__ inline bf16x8 pack8v(f32x4 a, f32x4 b) {
    bf16x8 r;
    r[0] = f2bfs(a[0]); r[1] = f2bfs(a[1]); r[2] = f2bfs(a[2]); r[3] = f2bfs(a[3]);
    r[4] = f2bfs(b[0]); r[5] = f2bfs(b[1]); r[6] = f2bfs(b[2]); r[7] = f2bfs(b[3]);
    return r;
}

__device__ inline int swzK(int r) { return (r & 3) | (((r >> 3) & 1) << 2); }
__device__ inline int swzV(int r) { return (r & 7) ^ ((r >> 3) & 7); }

// Raw barrier: flush own LDS ops, leave global/DMA loads in flight.
__device__ inline void wg_barrier() {
    asm volatile("s_waitcnt lgkmcnt(0)" ::: "memory");
    __builtin_amdgcn_s_barrier();
    __builtin_amdgcn_sched_barrier(0);
}

// Direct global->LDS DMA, 16B per lane. LDS dest = wave-uniform base + lane*16.
__device__ inline void gl_lds16(const ushort* g, ushort* l) {
    __builtin_amdgcn_global_load_lds((const __attribute__((address_space(1))) void*)g,
                                     (__attribute__((address_space(3))) void*)l, 16, 0, 0);
}

__global__ void detect_mask_kernel(const uint32_t* __restrict__ w, uint32_t* __restrict__ flag) {
    __shared__ int nonbin;
    if (threadIdx.x == 0) nonbin = 0;
    __syncthreads();
    int bad = 0;
    for (int i = threadIdx.x; i < 4096; i += 256) bad |= (w[i] > 1u) ? 1 : 0;
    if (bad) atomicOr(&nonbin, 1);
    __syncthreads();
    if (threadIdx.x == 0) *flag = (uint32_t)(nonbin != 0);
}

// K -> bf16, elementwise (8 elems/thread).
__global__ void convert_k_kernel(const float* __restrict__ src, ushort* __restrict__ dst) {
    const int i = blockIdx.x * 256 + threadIdx.x;
    f32x4 a = *(const f32x4*)(src + (size_t)i * 8);
    f32x4 b = *(const f32x4*)(src + (size_t)i * 8 + 4);
    *(bf16x8*)(dst + (size_t)i * 8) = pack8v(a, b);
}

// V -> transposed bf16 Vt[b][d][k] via LDS tile.
__global__ void convert_vt_kernel(const float* __restrict__ v, ushort* __restrict__ vt) {
    __shared__ alignas(16) float Lt[64][68];
    const int kt = blockIdx.x, b = blockIdx.y;
    const int tid = (int)threadIdx.x;
    const int r = tid >> 2, c4 = tid & 3;
    const float* vb = v + ((size_t)b * LL + kt * 64) * DD;
    #pragma unroll
    for (int j = 0; j < 4; ++j)
        *(f32x4*)&Lt[r][c4 * 16 + j * 4] = *(const f32x4*)(vb + (size_t)r * DD + c4 * 16 + j * 4);
    __syncthreads();
    ushort* vout = vt + (size_t)b * DD * LL + (size_t)r * LL + kt * 64 + c4 * 16;
    bf16x8 o0, o1;
    #pragma unroll
    for (int j = 0; j < 8; ++j) o0[j] = f2bfs(Lt[c4 * 16 + j][r]);
    #pragma unroll
    for (int j = 0; j < 8; ++j) o1[j] = f2bfs(Lt[c4 * 16 + 8 + j][r]);
    *(bf16x8*)vout = o0;
    *(bf16x8*)(vout + 8) = o1;
}

// R17 structure with a contract-exact DMA pipeline: all staging issues are
// UNCONDITIONAL with wrapped tile indices, so the counted s_waitcnt vmcnt(N)
// is exact on every iteration (R17's guarded issues made the final tiles'
// waits no-ops -- a latent race). Drains added before KB reuse / kernel end.
__global__ __launch_bounds__(512, 4) void fused_attn_kernel(
    const float* __restrict__ qg, const ushort* __restrict__ kbf,
    const ushort* __restrict__ vtb, const void* __restrict__ maskv,
    const uint32_t* __restrict__ flagp,
    float* __restrict__ attn, float* __restrict__ outp)
{
    __shared__ alignas(16) ushort KB[4][KT * 64];  // p1: K dbuf {0,1}, V^T dbuf {2,3}; p2: two 128-row K pairs
    __shared__ uint8_t Msk[8][NT][64];             // mask bits [wave][tile][lane] (32 KB)
    __shared__ float Rs[128];

    const int tid = (int)threadIdx.x;
    const int w   = tid >> 6, l = tid & 63;
    const int lr  = l & 15, lg = l >> 4;
    const int rg  = w & 3, ch = w >> 2;
    const int id  = (int)blockIdx.x;     // id = qt*8 + b
    const int b   = id & 7;
    const int q0  = (id >> 3) * 64;
    const bool mbyte = (*flagp != 0);

    const ushort* kb = kbf + (size_t)b * LL * DD;        // bf16 K [k][d]
    const ushort* vtg = vtb + (size_t)b * DD * LL;       // bf16 V^T [d][k]

    const int qrow = q0 + 16 * rg + lr;
    const uint8_t* mrow8  = (const uint8_t*)maskv + (size_t)b * LL * LL + (size_t)qrow * LL + ch * 32 + lg * 8;
    const int*     mrow32 = (const int*)maskv     + (size_t)b * LL * LL + (size_t)qrow * LL + ch * 32 + lg * 8;
    float* arow = attn + (size_t)b * LL * LL + (size_t)qrow * LL + ch * 32 + lg * 8;

    bf16x8 qf0, qf1;
    {
        const float* qp = qg + (size_t)(b * LL + qrow) * DD + lg * 8;
        qf0 = pack8v(*(const f32x4*)(qp)      * QSCALE, *(const f32x4*)(qp + 4)  * QSCALE);
        qf1 = pack8v(*(const f32x4*)(qp + 32) * QSCALE, *(const f32x4*)(qp + 36) * QSCALE);
    }

    // ---------- DMA staging ----------
    const int drow = w * 8 + (l >> 3);   // K row / V d-row staged by this lane
    const int dc   = l & 7;              // 16B chunk
    const int kchunk = dc ^ swzK(drow);  // pre-swizzled global chunk (K)
    const int vchunk = dc ^ swzV(drow);  // pre-swizzled global chunk (V^T)
    auto dmaK = [&](int kt, int buf) {
        gl_lds16(kb + (size_t)(kt * KT + drow) * 64 + 8 * kchunk, &KB[buf][w * 512]);
    };
    auto dmaV = [&](int kt, int buf) {
        gl_lds16(vtg + (size_t)drow * LL + kt * KT + 8 * vchunk, &KB[2 + buf][w * 512]);
    };
    auto dmaK2 = [&](int kt2, int pair) {
        gl_lds16(kb + (size_t)(kt2 * 128 + drow) * 64 + 8 * kchunk, &KB[2 * pair][w * 512]);
        gl_lds16(kb + (size_t)(kt2 * 128 + 64 + drow) * 64 + 8 * kchunk, &KB[2 * pair + 1][w * 512]);
    };
    unsigned long long mA = 0, mB = 0;
    #define ASM_MLOAD(dst, kt) { unsigned long long a_ = (unsigned long long)(uintptr_t)(mrow8 + (kt) * KT); \
        asm volatile("global_load_dwordx2 %0, %1, off" : "=v"(dst) : "v"(a_) : "memory"); }

    // ================= pass 1: rowsums + unnormalized PV (P in regs) =================
    float rsum = 0.f;
    f32x4 oacc[4];
    #pragma unroll
    for (int g = 0; g < 4; ++g) { f32x4 z = {0.f, 0.f, 0.f, 0.f}; oacc[g] = z; }

    auto body1 = [&](int buf, unsigned long long mu, int kt) {
        int4 mi0 = {0,0,0,0}, mi1 = {0,0,0,0};
        if (!mbyte) { mi0 = *(const int4*)(mrow32 + kt * KT); mi1 = *(const int4*)(mrow32 + kt * KT + 4); }
        uint32_t mbits = 0;
        float p8[8];
        __builtin_amdgcn_s_setprio(1);
        #pragma unroll
        for (int n = 0; n < 2; ++n) {
            const int krow = ch * 32 + ((lr >> 2) << 3) + (n << 2) + (lr & 3);
            bf16x8 k0 = *(const bf16x8*)&KB[buf][krow * 64 + ((lg       ^ swzK(krow)) << 3)];
            bf16x8 k1 = *(const bf16x8*)&KB[buf][krow * 64 + (((4 + lg) ^ swzK(krow)) << 3)];
            f32x4 c = {0.f, 0.f, 0.f, 0.f};
            c = __builtin_amdgcn_mfma_f32_16x16x32_bf16(k0, qf0, c, 0, 0, 0);
            c = __builtin_amdgcn_mfma_f32_16x16x32_bf16(k1, qf1, c, 0, 0, 0);
            #pragma unroll
            for (int j = 0; j < 4; ++j) {
                const int t = n * 4 + j;
                int mk;
                if (mbyte) mk = (int)((mu >> (8 * t)) & 0xffu);
                else {
                    const int4 mi = n ? mi1 : mi0;
                    mk = (j == 0) ? mi.x : (j == 1) ? mi.y : (j == 2) ? mi.z : mi.w;
                }
                mbits |= (mk ? 1u : 0u) << t;
                const float pv = mk ? 0.f : exp2f(c[j]);
                rsum += pv;
                p8[t] = pv;
            }
        }
        __builtin_amdgcn_s_setprio(0);
        Msk[w][kt][l] = (uint8_t)mbits;
        bf16x8 pa;
        #pragma unroll
        for (int t = 0; t < 8; ++t) pa[t] = f2bfs(p8[t]);
        __builtin_amdgcn_s_setprio(1);
        #pragma unroll
        for (int g = 0; g < 4; ++g) {
            const int d = g * 16 + lr;
            bf16x8 vf = *(const bf16x8*)&KB[2 + buf][d * 64 + (((ch * 4 + lg) ^ swzV(d)) << 3)];
            oacc[g] = __builtin_amdgcn_mfma_f32_16x16x32_bf16(pa, vf, oacc[g], 0, 0, 0);
        }
        __builtin_amdgcn_s_setprio(0);
    };

    // prologue: tiles 0 and 1 in flight (3 vm-ops per tile when mbyte, else 2)
    dmaK(0, 0); dmaV(0, 0); if (mbyte) ASM_MLOAD(mA, 0);
    dmaK(1, 1); dmaV(1, 1); if (mbyte) ASM_MLOAD(mB, 1);
    #pragma unroll 1
    for (int kt = 0; kt < NT; kt += 2) {
        // ---- even tile kt (buf0, mA) ----
        if (mbyte) asm volatile("s_waitcnt vmcnt(3)" ::: "memory");
        else       asm volatile("s_waitcnt vmcnt(2)" ::: "memory");
        __builtin_amdgcn_sched_barrier(0);
        wg_barrier();                       // tile kt staged for all waves
        body1(0, mA, kt);
        wg_barrier();                       // all waves done reading buf0
        {   // unconditional wrapped issue: vmcnt stays exact to the last iteration
            const int nx = (kt + 2) & (NT - 1);
            dmaK(nx, 0); dmaV(nx, 0); if (mbyte) ASM_MLOAD(mA, nx);
        }
        // ---- odd tile kt+1 (buf1, mB) ----
        if (mbyte) asm volatile("s_waitcnt vmcnt(3)" ::: "memory");
        else       asm volatile("s_waitcnt vmcnt(2)" ::: "memory");
        __builtin_amdgcn_sched_barrier(0);
        wg_barrier();
        body1(1, mB, kt + 1);
        wg_barrier();
        {
            const int nx = (kt + 3) & (NT - 1);
            dmaK(nx, 1); dmaV(nx, 1); if (mbyte) ASM_MLOAD(mB, nx);
        }
    }
    asm volatile("s_waitcnt vmcnt(0)" ::: "memory");   // drain wrapped stragglers before KB reuse

    rsum += __shfl_xor(rsum, 16, 64);
    rsum += __shfl_xor(rsum, 32, 64);
    if (lg == 0) Rs[ch * 64 + 16 * rg + lr] = rsum;
    __syncthreads();
    const float rinv = 1.0f / (Rs[16 * rg + lr] + Rs[64 + 16 * rg + lr]);

    // epilogue: combine ch halves of O via retired KB region
    float* OutL = (float*)KB;
    if (ch == 1) {
        #pragma unroll
        for (int g = 0; g < 4; ++g)
            #pragma unroll
            for (int j = 0; j < 4; ++j)
                OutL[rg * 1088 + (lg * 4 + j) * 68 + g * 16 + lr] = oacc[g][j];
    }
    __syncthreads();
    if (ch == 0) {
        #pragma unroll
        for (int j = 0; j < 4; ++j) {
            const int ql = 16 * rg + lg * 4 + j;
            const float ri = 1.0f / (Rs[ql] + Rs[64 + ql]);
            const size_t orow = (size_t)(b * LL + q0 + ql) * DD;
            #pragma unroll
            for (int g = 0; g < 4; ++g)
                outp[orow + g * 16 + lr] = (oacc[g][j] + OutL[rg * 1088 + (lg * 4 + j) * 68 + g * 16 + lr]) * ri;
        }
    }
    __syncthreads();   // OutL reads complete BEFORE pass-2 DMA restages KB

    // ================= pass 2: recompute + attn write (128-wide tiles) =================
    auto body2 = [&](int pair, int idx) {
        const int kbase2 = idx * 128;
        #pragma unroll
        for (int h = 0; h < 2; ++h) {
            const int mb2 = (int)Msk[w][2 * idx + h][l];
            const ushort* Kbuf = KB[2 * pair + h];
            __builtin_amdgcn_s_setprio(1);
            #pragma unroll
            for (int n = 0; n < 2; ++n) {
                const int krow = ch * 32 + ((lr >> 2) << 3) + (n << 2) + (lr & 3);
                bf16x8 k0 = *(const bf16x8*)&Kbuf[krow * 64 + ((lg       ^ swzK(krow)) << 3)];
                bf16x8 k1 = *(const bf16x8*)&Kbuf[krow * 64 + (((4 + lg) ^ swzK(krow)) << 3)];
                f32x4 c = {0.f, 0.f, 0.f, 0.f};
                c = __builtin_amdgcn_mfma_f32_16x16x32_bf16(k0, qf0, c, 0, 0, 0);
                c = __builtin_amdgcn_mfma_f32_16x16x32_bf16(k1, qf1, c, 0, 0, 0);
                f32x4 pv;
                #pragma unroll
                for (int j = 0; j < 4; ++j)
                    pv[j] = ((mb2 >> (n * 4 + j)) & 1) ? 0.f : exp2f(c[j]) * rinv;
                *(f32x4*)(arow + kbase2 + h * 64 + n * 4) = pv;
            }
            __builtin_amdgcn_s_setprio(0);
        }
    };

    dmaK2(0, 0); dmaK2(1, 1);
    #pragma unroll 1
    for (int kt2 = 0; kt2 < NP2; ++kt2) {
        const int pair = kt2 & 1;
        asm volatile("s_waitcnt vmcnt(2)" ::: "memory");   // K2(kt2) landed
        __builtin_amdgcn_sched_barrier(0);
        wg_barrier();
        body2(pair, kt2);
        wg_barrier();
        dmaK2((kt2 + 2) & (NP2 - 1), pair);                // unconditional wrapped
    }
    asm volatile("s_waitcnt vmcnt(0)" ::: "memory");       // drain before block exit
}

extern "C" void kernel_launch(void* const* d_in, const int* in_sizes, int n_in,
                              void* d_out, int out_size, void* d_ws, size_t ws_size,
                              hipStream_t stream) {
    const float* q = (const float*)d_in[0];
    const float* k = (const float*)d_in[1];
    const float* v = (const float*)d_in[2];
    const void* mask = d_in[3];
    float* attn = (float*)d_out;
    float* outp = attn + (size_t)BB * LL * LL;
    uint32_t* flagp = (uint32_t*)d_ws;
    ushort* kbf = (ushort*)((char*)d_ws + 4096);                 // bf16 K   [b][k][d], 4 MB
    ushort* vtb = kbf + (size_t)BB * LL * DD;                    // bf16 V^T [b][d][k], 4 MB

    detect_mask_kernel<<<1, 256, 0, stream>>>((const uint32_t*)mask, flagp);
    convert_k_kernel<<<dim3(BB * LL * DD / 8 / 256), 256, 0, stream>>>(k, kbf);
    convert_vt_kernel<<<dim3(LL / 64, BB), 256, 0, stream>>>(v, vtb);
    fused_attn_kernel<<<dim3((LL / 64) * BB), 512, 0, stream>>>(q, kbf, vtb, mask, flagp, attn, outp);
}